// Round 9
// baseline (318.688 us; speedup 1.0000x reference)
//
#include <hip/hip_runtime.h>
#include <hip/hip_bf16.h>

#define LSEQ   200
#define LPAD   208
#define EMB    32
#define TDIM   128
#define COND   160
#define ROWS   321
#define MASK_T 48
#define LL_LDB 80      // LL row stride bytes (64B data + 16B pad)

typedef __attribute__((ext_vector_type(8))) short          short8;
typedef __attribute__((ext_vector_type(8))) unsigned short ushort8_t;
typedef __attribute__((ext_vector_type(4))) float          f32x4;

__device__ __forceinline__ float bf2f(unsigned short u) {
    union { unsigned int i; float f; } v; v.i = ((unsigned int)u) << 16; return v.f;
}
__device__ __forceinline__ float asf(unsigned int u) {
    union { unsigned int i; float f; } v; v.i = u; return v.f;
}
__device__ __forceinline__ unsigned int f2bf(float f) {
    union { float f; unsigned int i; } v; v.f = f;
    unsigned int x = v.i;
    return ((x + 0x7fffu + ((x >> 16) & 1u)) >> 16);   // RNE, low 16
}
__device__ __forceinline__ unsigned int pack2(float lo, float hi) {
    return f2bf(lo) | (f2bf(hi) << 16);
}
__device__ __forceinline__ short8 pack8(f32x4 a, f32x4 b) {
    union { short8 s; unsigned int u[4]; } r;
    r.u[0] = pack2(a[0], a[1]); r.u[1] = pack2(a[2], a[3]);
    r.u[2] = pack2(b[0], b[1]); r.u[3] = pack2(b[2], b[3]);
    return r.s;
}

template<int CTRL>
__device__ __forceinline__ float dpp_add(float v) {
    const int x = __builtin_amdgcn_update_dpp(0, __float_as_int(v), CTRL, 0xf, 0xf, true);
    return v + __int_as_float(x);
}
__device__ __forceinline__ float red16(float v) {
    v = dpp_add<0x128>(v);   // row_ror:8
    v = dpp_add<0x124>(v);   // row_ror:4
    v = dpp_add<0x122>(v);   // row_ror:2
    v = dpp_add<0x121>(v);   // row_ror:1
    return v;
}

// ---- prep (49 blocks): te_tab[49][128] bf16; T1t[160][52] f32; te_t[128][52] bf16;
//      T2w3[49][16][16] bf16: T2w3[t][lc][T] = T2[t][T*16+lc] (T<10; rest unused);
//      row t==48 -> 0 (mask semantics).
__global__ void prep(const float* __restrict__ w1, const float* __restrict__ w2,
                     unsigned short* __restrict__ te_tab, float* __restrict__ T1t,
                     unsigned short* __restrict__ te_t, unsigned short* __restrict__ T2w3) {
    __shared__ float te128[TDIM];
    const int t = blockIdx.x, tid = threadIdx.x;
    if (tid < 64) {
        const float dv = __expf(-0.14391156f * (float)tid);  // 10000^(-tid/64)
        const float a  = (float)t * dv;
        const float s  = __sinf(a), c = __cosf(a);
        te128[2 * tid] = s; te128[2 * tid + 1] = c;
        ((unsigned int*)te_tab)[t * 64 + tid] = pack2(s, c);
    }
    __syncthreads();
    if (tid < COND) {
        float s1 = 0.0f, s2 = 0.0f;
        const float* w1r = w1 + tid * COND + EMB;
        const float* w2r = w2 + tid * COND + EMB;
        #pragma unroll 8
        for (int j = 0; j < TDIM; ++j) {
            s1 = fmaf(te128[j], w1r[j], s1);
            s2 = fmaf(te128[j], w2r[j], s2);
        }
        if (t == MASK_T) { s1 = 0.0f; s2 = 0.0f; }
        T1t[tid * 52 + t] = s1;
        const int tile = tid >> 4, lcc = tid & 15;
        T2w3[t * 256 + lcc * 16 + tile] = (unsigned short)f2bf(s2);
    }
    if (tid < TDIM) te_t[tid * 52 + t] = (unsigned short)f2bf(te128[tid]);
}

// ---- main: one batch per 256-thread block (4 waves), m-split GEMM ----
__global__ __launch_bounds__(256, 8)
void fused4(const int*   __restrict__ tp,
            const int*   __restrict__ loc,
            const float* __restrict__ emb,
            const int*   __restrict__ st,        // [B][L][2]
            const float* __restrict__ loc_emb,   // [V][32] fp32
            const float* __restrict__ noise,
            const int*   __restrict__ tstep,
            const float* __restrict__ w1,        // fp32 (cols 0..31 used)
            const float* __restrict__ w2,        // fp32 (cols 0..31 used)
            const unsigned short* __restrict__ te_tab,
            const float* __restrict__ T1t,       // [160][52]
            const unsigned short* __restrict__ te_t,   // [128][52]
            const unsigned short* __restrict__ T2w3,   // [49][16][16]
            const float* __restrict__ b2,
            const float* __restrict__ wc,
            const float* __restrict__ alpha_hat,
            float* __restrict__ out)             // [B][321][32]
{
    __shared__ __attribute__((aligned(16))) unsigned char LL[LPAD * LL_LDB]; // 16,640
    __shared__ float scoreW[LSEQ];                       // 800
    __shared__ float su[320];                            // 1,280 [side|uemb]
    __shared__ float m1W[COND];                          // 640
    __shared__ __attribute__((aligned(16))) float mupart[4][EMB];   // 512
    __shared__ __attribute__((aligned(16))) float cntsb[52];        // 208
    __shared__ __attribute__((aligned(4)))  unsigned char ttr[LPAD];// 208

    const int tid  = threadIdx.x;
    const int w    = tid >> 6, lane = tid & 63;
    const int b    = blockIdx.x;
    const int lc   = lane & 15, lg = lane >> 4;
    const int rsub = lane >> 3, csub = lane & 7;
    const int2* st2 = (const int2*)st;
    float* outb = out + (size_t)b * (ROWS * EMB);

    // ---- early independent loads: all 10 B-frags (w2 cols 0..31 -> bf16) + wc ----
    short8 bf[10]; float wcv[10];
    #pragma unroll
    for (int T = 0; T < 10; ++T) {
        const int c = T * 16 + lc;
        const f32x4* r = (const f32x4*)(w2 + (size_t)c * COND + lg * 8);
        bf[T]  = pack8(r[0], r[1]);
        wcv[T] = wc[c];
    }

    // ---- P0: side row, noisy row, zero-init ----
    if (w == 0) {
        if (lane < 32) {
            const ushort4 tv = *(const ushort4*)(te_tab + tp[b] * TDIM + lane * 4);
            f32x4 s4 = { bf2f(tv.x), bf2f(tv.y), bf2f(tv.z), bf2f(tv.w) };
            *(f32x4*)(su + lane * 4) = s4;
        } else if (lane < 40) {
            *(f32x4*)(su + 128 + (lane - 32) * 4) =
                *(const f32x4*)(loc_emb + (size_t)(loc[b] - 1) * EMB + (lane - 32) * 4);
        } else if (lane < 48) {
            const int e4 = lane - 40;
            const float a  = alpha_hat[tstep[b]];
            const float sa = sqrtf(a), sn = sqrtf(1.0f - a);
            const f32x4 ev = *(const f32x4*)(emb + (size_t)b * EMB + e4 * 4);
            const f32x4 nv = *(const f32x4*)(noise + (size_t)b * EMB + e4 * 4);
            f32x4 r = { sa*ev[0]+sn*nv[0], sa*ev[1]+sn*nv[1],
                        sa*ev[2]+sn*nv[2], sa*ev[3]+sn*nv[3] };
            *(f32x4*)(outb + 320 * EMB + e4 * 4) = r;
        }
    } else if (w == 1) {
        if (lane < 52) cntsb[lane] = 0.0f;
        if (lane >= 52 && lane < 60) {               // zero-pad rows 200..207
            const int r = 200 + lane - 52;
            uint4 z = make_uint4(0, 0, 0, 0);
            *(uint4*)(LL + r * LL_LDB)      = z;
            *(uint4*)(LL + r * LL_LDB + 16) = z;
            *(uint4*)(LL + r * LL_LDB + 32) = z;
            *(uint4*)(LL + r * LL_LDB + 48) = z;
            ttr[r] = 0;
        }
    }
    __syncthreads();   // B0

    // ---- P1a: ttr + cnt histogram (wave w owns rows w*50..w*50+49) ----
    int tA = MASK_T;
    if (lane < 50) {
        const int r = w * 50 + lane;
        const int2 sv = st2[(size_t)b * LSEQ + r];
        ttr[r] = (unsigned char)sv.y;
        tA = sv.y;
        if (sv.y != MASK_T) atomicAdd(&cntsb[sv.y], 1.0f);
    }

    // ---- P1b: quarter-row gather -> LL(bf16) + mean partials ----
    f32x4 macc = {0.f, 0.f, 0.f, 0.f};
    #pragma unroll
    for (int i = 0; i < 7; ++i) {
        const int rr = i * 8 + rsub;
        if (rr < 50) {
            const int row = w * 50 + rr;
            const int s0 = st2[(size_t)b * LSEQ + row].x - 1;
            const f32x4 v = *(const f32x4*)(loc_emb + (size_t)s0 * EMB + csub * 4);
            macc += v;
            uint2 pv = make_uint2(pack2(v[0], v[1]), pack2(v[2], v[3]));
            *(uint2*)(LL + row * LL_LDB + csub * 8) = pv;
        }
    }
    #pragma unroll
    for (int sh = 8; sh < 64; sh <<= 1) {
        macc[0] += __shfl_xor(macc[0], sh);
        macc[1] += __shfl_xor(macc[1], sh);
        macc[2] += __shfl_xor(macc[2], sh);
        macc[3] += __shfl_xor(macc[3], sh);
    }
    if (rsub == 0) *(f32x4*)(&mupart[w][csub * 4]) = macc;
    __syncthreads();   // B1

    // ---- P2: m1[c] = b2 + (colsum@w1[:, :32]^T + cnt@T1t)/200 ----
    if (tid < COND) {
        const int c = tid;
        f32x4 mm[8];
        #pragma unroll
        for (int j = 0; j < 8; ++j)
            mm[j] = ((const f32x4*)mupart[0])[j] + ((const f32x4*)mupart[1])[j]
                  + ((const f32x4*)mupart[2])[j] + ((const f32x4*)mupart[3])[j];
        f32x4 d = {0.f, 0.f, 0.f, 0.f};
        const f32x4* w1r = (const f32x4*)(w1 + (size_t)c * COND);
        #pragma unroll
        for (int j = 0; j < 8; ++j) d += mm[j] * w1r[j];
        const f32x4* t1r = (const f32x4*)(T1t + c * 52);
        #pragma unroll
        for (int q = 0; q < 13; ++q)
            d += ((const f32x4*)cntsb)[q] * t1r[q];
        m1W[c] = b2[c] + (d[0] + d[1] + d[2] + d[3]) * 0.005f;
    }
    __syncthreads();   // B2

    if (w == 1 && lane < 52) cntsb[lane] = 0.0f;   // re-zero as sb (read after B3)

    // ---- P3: per-tile m1 ----
    float m1v[10];
    #pragma unroll
    for (int T = 0; T < 10; ++T) m1v[T] = m1W[T * 16 + lc];

    // ---- P4: m-split GEMM: wave w owns m-tiles {0..3 | 4..6 | 7..9 | 10..12} ----
    const int ms   = (w == 0) ? 0 : 3 * w + 1;
    const int mcnt = (w == 0) ? 4 : 3;
    for (int mi = 0; mi < mcnt; ++mi) {
        const int m = ms + mi;
        const short8 av = *(const short8*)(LL + (m * 16 + lc) * LL_LDB + lg * 16);
        f32x4 acc[10];
        #pragma unroll
        for (int T = 0; T < 10; ++T) {
            f32x4 z = {0.f, 0.f, 0.f, 0.f};
            acc[T] = __builtin_amdgcn_mfma_f32_16x16x32_bf16(av, bf[T], z, 0, 0, 0);
        }
        const uchar4 tq = *(const uchar4*)(ttr + m * 16 + lg * 4);
        f32x4 srow;
        #pragma unroll
        for (int r = 0; r < 4; ++r) {
            const int t = (r == 0) ? tq.x : (r == 1) ? tq.y : (r == 2) ? tq.z : tq.w;
            const unsigned short* t2p = T2w3 + t * 256 + lc * 16;
            const ushort8_t qa = *(const ushort8_t*)(t2p);
            const ushort4   qb = *(const ushort4*)(t2p + 8);
            float s = 0.0f;
            #pragma unroll
            for (int T = 0; T < 10; ++T) {
                const unsigned short t2u = (T < 8) ? (unsigned short)qa[T]
                                         : (T == 8) ? qb.x : qb.y;
                const float x = acc[T][r] + m1v[T] + bf2f(t2u);
                s = fmaf(wcv[T], __builtin_amdgcn_rcpf(1.0f + __expf(-x)), s);
            }
            srow[r] = red16(s);
        }
        if (lc == 0) {
            #pragma unroll
            for (int r = 0; r < 4; ++r) {
                const int row = m * 16 + lg * 4 + r;
                if (row < LSEQ) scoreW[row] = srow[r];
            }
        }
    }
    __syncthreads();   // B3

    // ---- P5a: sb histogram ----
    if (lane < 50) {
        const float sc = scoreW[w * 50 + lane];
        if (tA != MASK_T) atomicAdd(&cntsb[tA], sc);
    }
    // ---- P5: uemb_loc quarter-row partials from LL ----
    f32x4 uacc = {0.f, 0.f, 0.f, 0.f};
    #pragma unroll
    for (int i = 0; i < 7; ++i) {
        const int rr = i * 8 + rsub;
        if (rr < 50) {
            const int row = w * 50 + rr;
            const float sc = scoreW[row];
            const uint2 pv = *(const uint2*)(LL + row * LL_LDB + csub * 8);
            uacc[0] = fmaf(sc, asf(pv.x << 16), uacc[0]);
            uacc[1] = fmaf(sc, asf(pv.x & 0xffff0000u), uacc[1]);
            uacc[2] = fmaf(sc, asf(pv.y << 16), uacc[2]);
            uacc[3] = fmaf(sc, asf(pv.y & 0xffff0000u), uacc[3]);
        }
    }
    #pragma unroll
    for (int sh = 8; sh < 64; sh <<= 1) {
        uacc[0] += __shfl_xor(uacc[0], sh);
        uacc[1] += __shfl_xor(uacc[1], sh);
        uacc[2] += __shfl_xor(uacc[2], sh);
        uacc[3] += __shfl_xor(uacc[3], sh);
    }
    if (rsub == 0) *(f32x4*)(&mupart[w][csub * 4]) = uacc;
    __syncthreads();   // B4

    // ---- P5b: uemb_te (tid<128) + uemb_loc combine (tid 128..159) ----
    if (tid < TDIM) {
        const int j = tid;
        const unsigned short* ter = te_t + j * 52;
        float s = 0.0f;
        #pragma unroll
        for (int q = 0; q < 13; ++q) {
            const f32x4 sq = ((const f32x4*)cntsb)[q];
            const ushort4 tv = *(const ushort4*)(ter + q * 4);
            s = fmaf(sq[0], bf2f(tv.x), s);
            s = fmaf(sq[1], bf2f(tv.y), s);
            s = fmaf(sq[2], bf2f(tv.z), s);
            s = fmaf(sq[3], bf2f(tv.w), s);
        }
        su[192 + j] = s;
    } else if (tid < TDIM + 32) {
        const int col = tid - TDIM;
        su[160 + col] = mupart[0][col] + mupart[1][col]
                      + mupart[2][col] + mupart[3][col];
    }
    __syncthreads();   // B5

    // ---- P6: broadcast-write rows 0..319 ----
    #pragma unroll
    for (int k = 0; k < 10; ++k) {
        const int idx = tid + k * 256;
        const int row = idx >> 3;
        const float v = su[row];
        f32x4 vv = {v, v, v, v};
        *(f32x4*)(outb + row * EMB + (idx & 7) * 4) = vv;
    }
}

extern "C" void kernel_launch(void* const* d_in, const int* in_sizes, int n_in,
                              void* d_out, int out_size, void* d_ws, size_t ws_size,
                              hipStream_t stream) {
    const int*   tp        = (const int*)  d_in[0];
    const int*   loc       = (const int*)  d_in[1];
    const float* emb       = (const float*)d_in[2];
    const int*   st        = (const int*)  d_in[3];
    const float* loc_emb   = (const float*)d_in[4];
    const float* noise     = (const float*)d_in[5];
    const int*   tstep     = (const int*)  d_in[6];
    const float* w1        = (const float*)d_in[7];
    const float* w2        = (const float*)d_in[8];
    const float* b2        = (const float*)d_in[9];
    const float* wc        = (const float*)d_in[10];
    const float* alpha_hat = (const float*)d_in[11];
    float* out = (float*)d_out;

    char* ws = (char*)d_ws;
    float*          T1t    = (float*)ws;                          // 33,280 B
    unsigned short* te_tab = (unsigned short*)(ws + 33280);       // 12,544 B
    unsigned short* te_t   = (unsigned short*)(ws + 45824);       // 13,312 B
    unsigned short* T2w3   = (unsigned short*)(ws + 59136);       // 25,088 B

    prep<<<49, 256, 0, stream>>>(w1, w2, te_tab, T1t, te_t, T2w3);

    const int nb = in_sizes[0];   // 2048
    fused4<<<nb, 256, 0, stream>>>(tp, loc, emb, st, loc_emb, noise, tstep,
                                   w1, w2, te_tab, T1t, te_t, T2w3,
                                   b2, wc, alpha_hat, out);
}

// Round 10
// 93.932 us; speedup vs baseline: 3.3927x; 3.3927x over previous
//
#include <hip/hip_runtime.h>
#include <hip/hip_bf16.h>

#define LSEQ   200
#define LPAD   208
#define EMB    32
#define TDIM   128
#define COND   160
#define ROWS   321
#define MASK_T 48
#define LL_LDB 80      // LL row stride bytes (64B data + 16B pad)

typedef __attribute__((ext_vector_type(8))) short          short8;
typedef __attribute__((ext_vector_type(8))) unsigned short ushort8_t;
typedef __attribute__((ext_vector_type(4))) float          f32x4;

__device__ __forceinline__ float bf2f(unsigned short u) {
    union { unsigned int i; float f; } v; v.i = ((unsigned int)u) << 16; return v.f;
}
__device__ __forceinline__ float asf(unsigned int u) {
    union { unsigned int i; float f; } v; v.i = u; return v.f;
}
__device__ __forceinline__ unsigned int f2bf(float f) {
    union { float f; unsigned int i; } v; v.f = f;
    unsigned int x = v.i;
    return ((x + 0x7fffu + ((x >> 16) & 1u)) >> 16);   // RNE, low 16
}
__device__ __forceinline__ unsigned int pack2(float lo, float hi) {
    return f2bf(lo) | (f2bf(hi) << 16);
}
__device__ __forceinline__ short8 pack8(f32x4 a, f32x4 b) {
    union { short8 s; unsigned int u[4]; } r;
    r.u[0] = pack2(a[0], a[1]); r.u[1] = pack2(a[2], a[3]);
    r.u[2] = pack2(b[0], b[1]); r.u[3] = pack2(b[2], b[3]);
    return r.s;
}

template<int CTRL>
__device__ __forceinline__ float dpp_add(float v) {
    const int x = __builtin_amdgcn_update_dpp(0, __float_as_int(v), CTRL, 0xf, 0xf, true);
    return v + __int_as_float(x);
}
__device__ __forceinline__ float red16(float v) {
    v = dpp_add<0x128>(v);   // row_ror:8
    v = dpp_add<0x124>(v);   // row_ror:4
    v = dpp_add<0x122>(v);   // row_ror:2
    v = dpp_add<0x121>(v);   // row_ror:1
    return v;
}

// ---- prep (49 blocks): te_tab[49][128] bf16; T1t[160][52] f32; te_t[128][52] bf16;
//      T2w3[49][16][16] bf16: T2w3[t][lc][T] = T2[t][T*16+lc] (T<10); row t==48 -> 0.
__global__ void prep(const float* __restrict__ w1, const float* __restrict__ w2,
                     unsigned short* __restrict__ te_tab, float* __restrict__ T1t,
                     unsigned short* __restrict__ te_t, unsigned short* __restrict__ T2w3) {
    __shared__ float te128[TDIM];
    const int t = blockIdx.x, tid = threadIdx.x;
    if (tid < 64) {
        const float dv = __expf(-0.14391156f * (float)tid);  // 10000^(-tid/64)
        const float a  = (float)t * dv;
        const float s  = __sinf(a), c = __cosf(a);
        te128[2 * tid] = s; te128[2 * tid + 1] = c;
        ((unsigned int*)te_tab)[t * 64 + tid] = pack2(s, c);
    }
    __syncthreads();
    if (tid < COND) {
        float s1 = 0.0f, s2 = 0.0f;
        const float* w1r = w1 + tid * COND + EMB;
        const float* w2r = w2 + tid * COND + EMB;
        #pragma unroll 8
        for (int j = 0; j < TDIM; ++j) {
            s1 = fmaf(te128[j], w1r[j], s1);
            s2 = fmaf(te128[j], w2r[j], s2);
        }
        if (t == MASK_T) { s1 = 0.0f; s2 = 0.0f; }
        T1t[tid * 52 + t] = s1;
        const int tile = tid >> 4, lcc = tid & 15;
        T2w3[t * 256 + lcc * 16 + tile] = (unsigned short)f2bf(s2);
    }
    if (tid < TDIM) te_t[tid * 52 + t] = (unsigned short)f2bf(te128[tid]);
}

// ---- main: one batch per 256-thread block (4 waves), m-split GEMM ----
__global__ __launch_bounds__(256, 4)
void fused4(const int*   __restrict__ tp,
            const int*   __restrict__ loc,
            const float* __restrict__ emb,
            const int*   __restrict__ st,        // [B][L][2]
            const float* __restrict__ loc_emb,   // [V][32] fp32
            const float* __restrict__ noise,
            const int*   __restrict__ tstep,
            const float* __restrict__ w1,        // fp32 (cols 0..31 used)
            const float* __restrict__ w2,        // fp32 (cols 0..31 used)
            const unsigned short* __restrict__ te_tab,
            const float* __restrict__ T1t,       // [160][52]
            const unsigned short* __restrict__ te_t,   // [128][52]
            const unsigned short* __restrict__ T2w3,   // [49][16][16]
            const float* __restrict__ b2,
            const float* __restrict__ wc,
            const float* __restrict__ alpha_hat,
            float* __restrict__ out)             // [B][321][32]
{
    __shared__ __attribute__((aligned(16))) unsigned char LL[LPAD * LL_LDB]; // 16,640
    __shared__ float scoreW[LSEQ];                       // 800
    __shared__ float su[320];                            // 1,280 [side|uemb]
    __shared__ float m1W[COND];                          // 640
    __shared__ __attribute__((aligned(16))) float mupart[4][EMB];   // 512
    __shared__ __attribute__((aligned(16))) float cntsb[52];        // 208
    __shared__ __attribute__((aligned(4)))  unsigned char ttr[LPAD];// 208

    const int tid  = threadIdx.x;
    const int w    = tid >> 6, lane = tid & 63;
    const int b    = blockIdx.x;
    const int lc   = lane & 15, lg = lane >> 4;
    const int rsub = lane >> 3, csub = lane & 7;
    const int2* st2 = (const int2*)st;
    float* outb = out + (size_t)b * (ROWS * EMB);

    // ---- early independent loads: all 10 B-frags (w2 cols 0..31 -> bf16) + wc ----
    short8 bf[10]; float wcv[10];
    #pragma unroll
    for (int T = 0; T < 10; ++T) {
        const int c = T * 16 + lc;
        const f32x4* r = (const f32x4*)(w2 + (size_t)c * COND + lg * 8);
        bf[T]  = pack8(r[0], r[1]);
        wcv[T] = wc[c];
    }

    // ---- P0: side row, noisy row, zero-init ----
    if (w == 0) {
        if (lane < 32) {
            const ushort4 tv = *(const ushort4*)(te_tab + tp[b] * TDIM + lane * 4);
            f32x4 s4 = { bf2f(tv.x), bf2f(tv.y), bf2f(tv.z), bf2f(tv.w) };
            *(f32x4*)(su + lane * 4) = s4;
        } else if (lane < 40) {
            *(f32x4*)(su + 128 + (lane - 32) * 4) =
                *(const f32x4*)(loc_emb + (size_t)(loc[b] - 1) * EMB + (lane - 32) * 4);
        } else if (lane < 48) {
            const int e4 = lane - 40;
            const float a  = alpha_hat[tstep[b]];
            const float sa = sqrtf(a), sn = sqrtf(1.0f - a);
            const f32x4 ev = *(const f32x4*)(emb + (size_t)b * EMB + e4 * 4);
            const f32x4 nv = *(const f32x4*)(noise + (size_t)b * EMB + e4 * 4);
            f32x4 r = { sa*ev[0]+sn*nv[0], sa*ev[1]+sn*nv[1],
                        sa*ev[2]+sn*nv[2], sa*ev[3]+sn*nv[3] };
            *(f32x4*)(outb + 320 * EMB + e4 * 4) = r;
        }
    } else if (w == 1) {
        if (lane < 52) cntsb[lane] = 0.0f;
        if (lane >= 52 && lane < 60) {               // zero-pad rows 200..207
            const int r = 200 + lane - 52;
            uint4 z = make_uint4(0, 0, 0, 0);
            *(uint4*)(LL + r * LL_LDB)      = z;
            *(uint4*)(LL + r * LL_LDB + 16) = z;
            *(uint4*)(LL + r * LL_LDB + 32) = z;
            *(uint4*)(LL + r * LL_LDB + 48) = z;
            ttr[r] = 0;
        }
    }
    __syncthreads();   // B0

    // ---- P1a: ttr + cnt histogram (wave w owns rows w*50..w*50+49) ----
    int tA = MASK_T;
    if (lane < 50) {
        const int r = w * 50 + lane;
        const int2 sv = st2[(size_t)b * LSEQ + r];
        ttr[r] = (unsigned char)sv.y;
        tA = sv.y;
        if (sv.y != MASK_T) atomicAdd(&cntsb[sv.y], 1.0f);
    }

    // ---- P1b: quarter-row gather -> LL(bf16) + mean partials ----
    f32x4 macc = {0.f, 0.f, 0.f, 0.f};
    #pragma unroll
    for (int i = 0; i < 7; ++i) {
        const int rr = i * 8 + rsub;
        if (rr < 50) {
            const int row = w * 50 + rr;
            const int s0 = st2[(size_t)b * LSEQ + row].x - 1;
            const f32x4 v = *(const f32x4*)(loc_emb + (size_t)s0 * EMB + csub * 4);
            macc += v;
            uint2 pv = make_uint2(pack2(v[0], v[1]), pack2(v[2], v[3]));
            *(uint2*)(LL + row * LL_LDB + csub * 8) = pv;
        }
    }
    #pragma unroll
    for (int sh = 8; sh < 64; sh <<= 1) {
        macc[0] += __shfl_xor(macc[0], sh);
        macc[1] += __shfl_xor(macc[1], sh);
        macc[2] += __shfl_xor(macc[2], sh);
        macc[3] += __shfl_xor(macc[3], sh);
    }
    if (rsub == 0) *(f32x4*)(&mupart[w][csub * 4]) = macc;
    __syncthreads();   // B1

    // ---- P2: m1[c] = b2 + (colsum@w1[:, :32]^T + cnt@T1t)/200 ----
    if (tid < COND) {
        const int c = tid;
        f32x4 mm[8];
        #pragma unroll
        for (int j = 0; j < 8; ++j)
            mm[j] = ((const f32x4*)mupart[0])[j] + ((const f32x4*)mupart[1])[j]
                  + ((const f32x4*)mupart[2])[j] + ((const f32x4*)mupart[3])[j];
        f32x4 d = {0.f, 0.f, 0.f, 0.f};
        const f32x4* w1r = (const f32x4*)(w1 + (size_t)c * COND);
        #pragma unroll
        for (int j = 0; j < 8; ++j) d += mm[j] * w1r[j];
        const f32x4* t1r = (const f32x4*)(T1t + c * 52);
        #pragma unroll
        for (int q = 0; q < 13; ++q)
            d += ((const f32x4*)cntsb)[q] * t1r[q];
        m1W[c] = b2[c] + (d[0] + d[1] + d[2] + d[3]) * 0.005f;
    }
    __syncthreads();   // B2

    if (w == 1 && lane < 52) cntsb[lane] = 0.0f;   // re-zero as sb (read after B3)

    // ---- P3: per-tile m1 ----
    float m1v[10];
    #pragma unroll
    for (int T = 0; T < 10; ++T) m1v[T] = m1W[T * 16 + lc];

    // ---- P4: m-split GEMM, two n-groups of 5 (caps live acc at 5 f32x4) ----
    const int ms   = (w == 0) ? 0 : 3 * w + 1;
    const int mcnt = (w == 0) ? 4 : 3;
    for (int mi = 0; mi < mcnt; ++mi) {
        const int m = ms + mi;
        const short8 av = *(const short8*)(LL + (m * 16 + lc) * LL_LDB + lg * 16);
        const uchar4 tq = *(const uchar4*)(ttr + m * 16 + lg * 4);
        float s4[4] = {0.f, 0.f, 0.f, 0.f};

        #pragma unroll
        for (int g = 0; g < 2; ++g) {
            f32x4 acc[5];
            #pragma unroll
            for (int T5 = 0; T5 < 5; ++T5) {
                f32x4 z = {0.f, 0.f, 0.f, 0.f};
                acc[T5] = __builtin_amdgcn_mfma_f32_16x16x32_bf16(av, bf[g * 5 + T5], z, 0, 0, 0);
            }
            #pragma unroll
            for (int r = 0; r < 4; ++r) {
                const int t = (r == 0) ? tq.x : (r == 1) ? tq.y : (r == 2) ? tq.z : tq.w;
                const unsigned short* t2p = T2w3 + t * 256 + lc * 16 + g * 5;
                const ushort4 qa = *(const ushort4*)(t2p);      // T = g*5 + 0..3
                const unsigned short q4 = t2p[4];               // T = g*5 + 4
                #pragma unroll
                for (int T5 = 0; T5 < 5; ++T5) {
                    const int T = g * 5 + T5;
                    const unsigned short t2u =
                        (T5 == 0) ? qa.x : (T5 == 1) ? qa.y :
                        (T5 == 2) ? qa.z : (T5 == 3) ? qa.w : q4;
                    const float x = acc[T5][r] + m1v[T] + bf2f(t2u);
                    s4[r] = fmaf(wcv[T], __builtin_amdgcn_rcpf(1.0f + __expf(-x)), s4[r]);
                }
            }
        }
        f32x4 srow;
        srow[0] = red16(s4[0]); srow[1] = red16(s4[1]);
        srow[2] = red16(s4[2]); srow[3] = red16(s4[3]);
        if (lc == 0) {
            #pragma unroll
            for (int r = 0; r < 4; ++r) {
                const int row = m * 16 + lg * 4 + r;
                if (row < LSEQ) scoreW[row] = srow[r];
            }
        }
    }
    __syncthreads();   // B3

    // ---- P5a: sb histogram ----
    if (lane < 50) {
        const float sc = scoreW[w * 50 + lane];
        if (tA != MASK_T) atomicAdd(&cntsb[tA], sc);
    }
    // ---- P5: uemb_loc quarter-row partials from LL ----
    f32x4 uacc = {0.f, 0.f, 0.f, 0.f};
    #pragma unroll
    for (int i = 0; i < 7; ++i) {
        const int rr = i * 8 + rsub;
        if (rr < 50) {
            const int row = w * 50 + rr;
            const float sc = scoreW[row];
            const uint2 pv = *(const uint2*)(LL + row * LL_LDB + csub * 8);
            uacc[0] = fmaf(sc, asf(pv.x << 16), uacc[0]);
            uacc[1] = fmaf(sc, asf(pv.x & 0xffff0000u), uacc[1]);
            uacc[2] = fmaf(sc, asf(pv.y << 16), uacc[2]);
            uacc[3] = fmaf(sc, asf(pv.y & 0xffff0000u), uacc[3]);
        }
    }
    #pragma unroll
    for (int sh = 8; sh < 64; sh <<= 1) {
        uacc[0] += __shfl_xor(uacc[0], sh);
        uacc[1] += __shfl_xor(uacc[1], sh);
        uacc[2] += __shfl_xor(uacc[2], sh);
        uacc[3] += __shfl_xor(uacc[3], sh);
    }
    if (rsub == 0) *(f32x4*)(&mupart[w][csub * 4]) = uacc;
    __syncthreads();   // B4

    // ---- P5b: uemb_te (tid<128) + uemb_loc combine (tid 128..159) ----
    if (tid < TDIM) {
        const int j = tid;
        const unsigned short* ter = te_t + j * 52;
        float s = 0.0f;
        #pragma unroll
        for (int q = 0; q < 13; ++q) {
            const f32x4 sq = ((const f32x4*)cntsb)[q];
            const ushort4 tv = *(const ushort4*)(ter + q * 4);
            s = fmaf(sq[0], bf2f(tv.x), s);
            s = fmaf(sq[1], bf2f(tv.y), s);
            s = fmaf(sq[2], bf2f(tv.z), s);
            s = fmaf(sq[3], bf2f(tv.w), s);
        }
        su[192 + j] = s;
    } else if (tid < TDIM + 32) {
        const int col = tid - TDIM;
        su[160 + col] = mupart[0][col] + mupart[1][col]
                      + mupart[2][col] + mupart[3][col];
    }
    __syncthreads();   // B5

    // ---- P6: broadcast-write rows 0..319 ----
    #pragma unroll
    for (int k = 0; k < 10; ++k) {
        const int idx = tid + k * 256;
        const int row = idx >> 3;
        const float v = su[row];
        f32x4 vv = {v, v, v, v};
        *(f32x4*)(outb + row * EMB + (idx & 7) * 4) = vv;
    }
}

extern "C" void kernel_launch(void* const* d_in, const int* in_sizes, int n_in,
                              void* d_out, int out_size, void* d_ws, size_t ws_size,
                              hipStream_t stream) {
    const int*   tp        = (const int*)  d_in[0];
    const int*   loc       = (const int*)  d_in[1];
    const float* emb       = (const float*)d_in[2];
    const int*   st        = (const int*)  d_in[3];
    const float* loc_emb   = (const float*)d_in[4];
    const float* noise     = (const float*)d_in[5];
    const int*   tstep     = (const int*)  d_in[6];
    const float* w1        = (const float*)d_in[7];
    const float* w2        = (const float*)d_in[8];
    const float* b2        = (const float*)d_in[9];
    const float* wc        = (const float*)d_in[10];
    const float* alpha_hat = (const float*)d_in[11];
    float* out = (float*)d_out;

    char* ws = (char*)d_ws;
    float*          T1t    = (float*)ws;                          // 33,280 B
    unsigned short* te_tab = (unsigned short*)(ws + 33280);       // 12,544 B
    unsigned short* te_t   = (unsigned short*)(ws + 45824);       // 13,312 B
    unsigned short* T2w3   = (unsigned short*)(ws + 59136);       // 25,088 B

    prep<<<49, 256, 0, stream>>>(w1, w2, te_tab, T1t, te_t, T2w3);

    const int nb = in_sizes[0];   // 2048
    fused4<<<nb, 256, 0, stream>>>(tp, loc, emb, st, loc_emb, noise, tstep,
                                   w1, w2, te_tab, T1t, te_t, T2w3,
                                   b2, wc, alpha_hat, out);
}

// Round 11
// 71.504 us; speedup vs baseline: 4.4570x; 1.3137x over previous
//
#include <hip/hip_runtime.h>
#include <hip/hip_bf16.h>

#define LSEQ   200
#define LPAD   208
#define EMB    32
#define TDIM   128
#define COND   160
#define ROWS   321
#define MASK_T 48
#define LL_LDB 80      // LL row stride bytes (64B data + 16B pad)

typedef __attribute__((ext_vector_type(8))) short          short8;
typedef __attribute__((ext_vector_type(4))) float          f32x4;

__device__ __forceinline__ float bf2f(unsigned short u) {
    union { unsigned int i; float f; } v; v.i = ((unsigned int)u) << 16; return v.f;
}
__device__ __forceinline__ float asf(unsigned int u) {
    union { unsigned int i; float f; } v; v.i = u; return v.f;
}
__device__ __forceinline__ unsigned int f2bf(float f) {
    union { float f; unsigned int i; } v; v.f = f;
    unsigned int x = v.i;
    return ((x + 0x7fffu + ((x >> 16) & 1u)) >> 16);   // RNE, low 16
}
__device__ __forceinline__ unsigned int pack2(float lo, float hi) {
    return f2bf(lo) | (f2bf(hi) << 16);
}

template<int CTRL>
__device__ __forceinline__ float dpp_add(float v) {
    const int x = __builtin_amdgcn_update_dpp(0, __float_as_int(v), CTRL, 0xf, 0xf, true);
    return v + __int_as_float(x);
}
__device__ __forceinline__ float red16(float v) {
    v = dpp_add<0x128>(v);   // row_ror:8
    v = dpp_add<0x124>(v);   // row_ror:4
    v = dpp_add<0x122>(v);   // row_ror:2
    v = dpp_add<0x121>(v);   // row_ror:1
    return v;
}

// ---- prep (49 blocks): te_tab[49][128] bf16; T1t[160][52] f32; te_t[128][52] bf16;
//      T2w3[49][16][16] bf16: T2w3[t][lc][T] = T2[t][T*16+lc] (T<10); row t==48 -> 0.
//      Block 0 additionally emits w2b[160][32] bf16 (w2 cols 0..31, frag-ready).
__global__ void prep(const float* __restrict__ w1, const float* __restrict__ w2,
                     unsigned short* __restrict__ te_tab, float* __restrict__ T1t,
                     unsigned short* __restrict__ te_t, unsigned short* __restrict__ T2w3,
                     unsigned short* __restrict__ w2b) {
    __shared__ float te128[TDIM];
    const int t = blockIdx.x, tid = threadIdx.x;
    if (tid < 64) {
        const float dv = __expf(-0.14391156f * (float)tid);  // 10000^(-tid/64)
        const float a  = (float)t * dv;
        const float s  = __sinf(a), c = __cosf(a);
        te128[2 * tid] = s; te128[2 * tid + 1] = c;
        ((unsigned int*)te_tab)[t * 64 + tid] = pack2(s, c);
    }
    __syncthreads();
    if (tid < COND) {
        float s1 = 0.0f, s2 = 0.0f;
        const float* w1r = w1 + tid * COND + EMB;
        const float* w2r = w2 + tid * COND + EMB;
        #pragma unroll 8
        for (int j = 0; j < TDIM; ++j) {
            s1 = fmaf(te128[j], w1r[j], s1);
            s2 = fmaf(te128[j], w2r[j], s2);
        }
        if (t == MASK_T) { s1 = 0.0f; s2 = 0.0f; }
        T1t[tid * 52 + t] = s1;
        const int tile = tid >> 4, lcc = tid & 15;
        T2w3[t * 256 + lcc * 16 + tile] = (unsigned short)f2bf(s2);
    }
    if (tid < TDIM) te_t[tid * 52 + t] = (unsigned short)f2bf(te128[tid]);
    if (t == 0 && tid < COND) {       // w2b row tid: cols 0..31 -> bf16
        const float* src = w2 + (size_t)tid * COND;
        unsigned int* dst = (unsigned int*)(w2b + tid * 32);
        #pragma unroll
        for (int j = 0; j < 16; ++j)
            dst[j] = pack2(src[2 * j], src[2 * j + 1]);
    }
}

// ---- main: one batch per 256-thread block (4 waves), m-split GEMM ----
__global__ __launch_bounds__(256) __attribute__((amdgpu_waves_per_eu(4, 4)))
void fused4(const int*   __restrict__ tp,
            const int*   __restrict__ loc,
            const float* __restrict__ emb,
            const int*   __restrict__ st,        // [B][L][2]
            const float* __restrict__ loc_emb,   // [V][32] fp32
            const float* __restrict__ noise,
            const int*   __restrict__ tstep,
            const float* __restrict__ w1,        // fp32 (cols 0..31 used)
            const unsigned short* __restrict__ w2b,    // [160][32] bf16
            const unsigned short* __restrict__ te_tab,
            const float* __restrict__ T1t,       // [160][52]
            const unsigned short* __restrict__ te_t,   // [128][52]
            const unsigned short* __restrict__ T2w3,   // [49][16][16]
            const float* __restrict__ b2,
            const float* __restrict__ wc,
            const float* __restrict__ alpha_hat,
            float* __restrict__ out)             // [B][321][32]
{
    __shared__ __attribute__((aligned(16))) unsigned char LL[LPAD * LL_LDB]; // 16,640
    __shared__ float scoreW[LSEQ];                       // 800
    __shared__ float su[320];                            // 1,280 [side|uemb]
    __shared__ float m1W[COND];                          // 640
    __shared__ __attribute__((aligned(16))) float mupart[4][EMB];   // 512
    __shared__ __attribute__((aligned(16))) float cntsb[52];        // 208
    __shared__ __attribute__((aligned(4)))  unsigned char ttr[LPAD];// 208

    const int tid  = threadIdx.x;
    const int w    = tid >> 6, lane = tid & 63;
    const int b    = blockIdx.x;
    const int lc   = lane & 15, lg = lane >> 4;
    const int rsub = lane >> 3, csub = lane & 7;
    const int2* st2 = (const int2*)st;
    float* outb = out + (size_t)b * (ROWS * EMB);

    // ---- early independent loads: all 10 B-frags (bf16, direct) + wc ----
    short8 bf[10]; float wcv[10];
    #pragma unroll
    for (int T = 0; T < 10; ++T) {
        const int c = T * 16 + lc;
        bf[T]  = *(const short8*)(w2b + c * 32 + lg * 8);
        wcv[T] = wc[c];
    }

    // ---- P0: side row, noisy row, zero-init ----
    if (w == 0) {
        if (lane < 32) {
            const ushort4 tv = *(const ushort4*)(te_tab + tp[b] * TDIM + lane * 4);
            f32x4 s4 = { bf2f(tv.x), bf2f(tv.y), bf2f(tv.z), bf2f(tv.w) };
            *(f32x4*)(su + lane * 4) = s4;
        } else if (lane < 40) {
            *(f32x4*)(su + 128 + (lane - 32) * 4) =
                *(const f32x4*)(loc_emb + (size_t)(loc[b] - 1) * EMB + (lane - 32) * 4);
        } else if (lane < 48) {
            const int e4 = lane - 40;
            const float a  = alpha_hat[tstep[b]];
            const float sa = sqrtf(a), sn = sqrtf(1.0f - a);
            const f32x4 ev = *(const f32x4*)(emb + (size_t)b * EMB + e4 * 4);
            const f32x4 nv = *(const f32x4*)(noise + (size_t)b * EMB + e4 * 4);
            f32x4 r = { sa*ev[0]+sn*nv[0], sa*ev[1]+sn*nv[1],
                        sa*ev[2]+sn*nv[2], sa*ev[3]+sn*nv[3] };
            *(f32x4*)(outb + 320 * EMB + e4 * 4) = r;
        }
    } else if (w == 1) {
        if (lane < 52) cntsb[lane] = 0.0f;
        if (lane >= 52 && lane < 60) {               // zero-pad rows 200..207
            const int r = 200 + lane - 52;
            uint4 z = make_uint4(0, 0, 0, 0);
            *(uint4*)(LL + r * LL_LDB)      = z;
            *(uint4*)(LL + r * LL_LDB + 16) = z;
            *(uint4*)(LL + r * LL_LDB + 32) = z;
            *(uint4*)(LL + r * LL_LDB + 48) = z;
            ttr[r] = 0;
        }
    }
    __syncthreads();   // B0

    // ---- P1a: ttr + cnt histogram (wave w owns rows w*50..w*50+49) ----
    int tA = MASK_T;
    if (lane < 50) {
        const int r = w * 50 + lane;
        const int2 sv = st2[(size_t)b * LSEQ + r];
        ttr[r] = (unsigned char)sv.y;
        tA = sv.y;
        if (sv.y != MASK_T) atomicAdd(&cntsb[sv.y], 1.0f);
    }

    // ---- P1b: quarter-row gather -> LL(bf16) + mean partials ----
    f32x4 macc = {0.f, 0.f, 0.f, 0.f};
    #pragma unroll
    for (int i = 0; i < 7; ++i) {
        const int rr = i * 8 + rsub;
        if (rr < 50) {
            const int row = w * 50 + rr;
            const int s0 = st2[(size_t)b * LSEQ + row].x - 1;
            const f32x4 v = *(const f32x4*)(loc_emb + (size_t)s0 * EMB + csub * 4);
            macc += v;
            uint2 pv = make_uint2(pack2(v[0], v[1]), pack2(v[2], v[3]));
            *(uint2*)(LL + row * LL_LDB + csub * 8) = pv;
        }
    }
    #pragma unroll
    for (int sh = 8; sh < 64; sh <<= 1) {
        macc[0] += __shfl_xor(macc[0], sh);
        macc[1] += __shfl_xor(macc[1], sh);
        macc[2] += __shfl_xor(macc[2], sh);
        macc[3] += __shfl_xor(macc[3], sh);
    }
    if (rsub == 0) *(f32x4*)(&mupart[w][csub * 4]) = macc;
    __syncthreads();   // B1

    // ---- P2: m1[c] = b2 + (colsum@w1[:, :32]^T + cnt@T1t)/200 ----
    if (tid < COND) {
        const int c = tid;
        f32x4 mm[8];
        #pragma unroll
        for (int j = 0; j < 8; ++j)
            mm[j] = ((const f32x4*)mupart[0])[j] + ((const f32x4*)mupart[1])[j]
                  + ((const f32x4*)mupart[2])[j] + ((const f32x4*)mupart[3])[j];
        f32x4 d = {0.f, 0.f, 0.f, 0.f};
        const f32x4* w1r = (const f32x4*)(w1 + (size_t)c * COND);
        #pragma unroll
        for (int j = 0; j < 8; ++j) d += mm[j] * w1r[j];
        const f32x4* t1r = (const f32x4*)(T1t + c * 52);
        #pragma unroll
        for (int q = 0; q < 13; ++q)
            d += ((const f32x4*)cntsb)[q] * t1r[q];
        m1W[c] = b2[c] + (d[0] + d[1] + d[2] + d[3]) * 0.005f;
    }
    __syncthreads();   // B2

    if (w == 1 && lane < 52) cntsb[lane] = 0.0f;   // re-zero as sb (read after B3)

    // ---- P3: per-tile m1 ----
    float m1v[10];
    #pragma unroll
    for (int T = 0; T < 10; ++T) m1v[T] = m1W[T * 16 + lc];

    // ---- P4: m-split GEMM, two n-groups of 5 (caps live acc at 5 f32x4) ----
    const int ms   = (w == 0) ? 0 : 3 * w + 1;
    const int mcnt = (w == 0) ? 4 : 3;
    for (int mi = 0; mi < mcnt; ++mi) {
        const int m = ms + mi;
        const short8 av = *(const short8*)(LL + (m * 16 + lc) * LL_LDB + lg * 16);
        const uchar4 tq = *(const uchar4*)(ttr + m * 16 + lg * 4);
        float s4[4] = {0.f, 0.f, 0.f, 0.f};

        #pragma unroll
        for (int g = 0; g < 2; ++g) {
            f32x4 acc[5];
            #pragma unroll
            for (int T5 = 0; T5 < 5; ++T5) {
                f32x4 z = {0.f, 0.f, 0.f, 0.f};
                acc[T5] = __builtin_amdgcn_mfma_f32_16x16x32_bf16(av, bf[g * 5 + T5], z, 0, 0, 0);
            }
            #pragma unroll
            for (int r = 0; r < 4; ++r) {
                const int t = (r == 0) ? tq.x : (r == 1) ? tq.y : (r == 2) ? tq.z : tq.w;
                const unsigned short* t2p = T2w3 + t * 256 + lc * 16 + g * 5;
                const ushort4 qa = *(const ushort4*)(t2p);      // T = g*5 + 0..3
                const unsigned short q4 = t2p[4];               // T = g*5 + 4
                #pragma unroll
                for (int T5 = 0; T5 < 5; ++T5) {
                    const int T = g * 5 + T5;
                    const unsigned short t2u =
                        (T5 == 0) ? qa.x : (T5 == 1) ? qa.y :
                        (T5 == 2) ? qa.z : (T5 == 3) ? qa.w : q4;
                    const float x = acc[T5][r] + m1v[T] + bf2f(t2u);
                    s4[r] = fmaf(wcv[T], __builtin_amdgcn_rcpf(1.0f + __expf(-x)), s4[r]);
                }
            }
        }
        f32x4 srow;
        srow[0] = red16(s4[0]); srow[1] = red16(s4[1]);
        srow[2] = red16(s4[2]); srow[3] = red16(s4[3]);
        if (lc == 0) {
            #pragma unroll
            for (int r = 0; r < 4; ++r) {
                const int row = m * 16 + lg * 4 + r;
                if (row < LSEQ) scoreW[row] = srow[r];
            }
        }
    }
    __syncthreads();   // B3

    // ---- P5a: sb histogram ----
    if (lane < 50) {
        const float sc = scoreW[w * 50 + lane];
        if (tA != MASK_T) atomicAdd(&cntsb[tA], sc);
    }
    // ---- P5: uemb_loc quarter-row partials from LL ----
    f32x4 uacc = {0.f, 0.f, 0.f, 0.f};
    #pragma unroll
    for (int i = 0; i < 7; ++i) {
        const int rr = i * 8 + rsub;
        if (rr < 50) {
            const int row = w * 50 + rr;
            const float sc = scoreW[row];
            const uint2 pv = *(const uint2*)(LL + row * LL_LDB + csub * 8);
            uacc[0] = fmaf(sc, asf(pv.x << 16), uacc[0]);
            uacc[1] = fmaf(sc, asf(pv.x & 0xffff0000u), uacc[1]);
            uacc[2] = fmaf(sc, asf(pv.y << 16), uacc[2]);
            uacc[3] = fmaf(sc, asf(pv.y & 0xffff0000u), uacc[3]);
        }
    }
    #pragma unroll
    for (int sh = 8; sh < 64; sh <<= 1) {
        uacc[0] += __shfl_xor(uacc[0], sh);
        uacc[1] += __shfl_xor(uacc[1], sh);
        uacc[2] += __shfl_xor(uacc[2], sh);
        uacc[3] += __shfl_xor(uacc[3], sh);
    }
    if (rsub == 0) *(f32x4*)(&mupart[w][csub * 4]) = uacc;
    __syncthreads();   // B4

    // ---- P5b: uemb_te (tid<128) + uemb_loc combine (tid 128..159) ----
    if (tid < TDIM) {
        const int j = tid;
        const unsigned short* ter = te_t + j * 52;
        float s = 0.0f;
        #pragma unroll
        for (int q = 0; q < 13; ++q) {
            const f32x4 sq = ((const f32x4*)cntsb)[q];
            const ushort4 tv = *(const ushort4*)(ter + q * 4);
            s = fmaf(sq[0], bf2f(tv.x), s);
            s = fmaf(sq[1], bf2f(tv.y), s);
            s = fmaf(sq[2], bf2f(tv.z), s);
            s = fmaf(sq[3], bf2f(tv.w), s);
        }
        su[192 + j] = s;
    } else if (tid < TDIM + 32) {
        const int col = tid - TDIM;
        su[160 + col] = mupart[0][col] + mupart[1][col]
                      + mupart[2][col] + mupart[3][col];
    }
    __syncthreads();   // B5

    // ---- P6: broadcast-write rows 0..319 ----
    #pragma unroll
    for (int k = 0; k < 10; ++k) {
        const int idx = tid + k * 256;
        const int row = idx >> 3;
        const float v = su[row];
        f32x4 vv = {v, v, v, v};
        *(f32x4*)(outb + row * EMB + (idx & 7) * 4) = vv;
    }
}

extern "C" void kernel_launch(void* const* d_in, const int* in_sizes, int n_in,
                              void* d_out, int out_size, void* d_ws, size_t ws_size,
                              hipStream_t stream) {
    const int*   tp        = (const int*)  d_in[0];
    const int*   loc       = (const int*)  d_in[1];
    const float* emb       = (const float*)d_in[2];
    const int*   st        = (const int*)  d_in[3];
    const float* loc_emb   = (const float*)d_in[4];
    const float* noise     = (const float*)d_in[5];
    const int*   tstep     = (const int*)  d_in[6];
    const float* w1        = (const float*)d_in[7];
    const float* w2        = (const float*)d_in[8];
    const float* b2        = (const float*)d_in[9];
    const float* wc        = (const float*)d_in[10];
    const float* alpha_hat = (const float*)d_in[11];
    float* out = (float*)d_out;

    char* ws = (char*)d_ws;
    float*          T1t    = (float*)ws;                          // 33,280 B
    unsigned short* te_tab = (unsigned short*)(ws + 33280);       // 12,544 B
    unsigned short* te_t   = (unsigned short*)(ws + 45824);       // 13,312 B
    unsigned short* T2w3   = (unsigned short*)(ws + 59136);       // 25,088 B
    unsigned short* w2b    = (unsigned short*)(ws + 84224);       // 10,240 B

    prep<<<49, 256, 0, stream>>>(w1, w2, te_tab, T1t, te_t, T2w3, w2b);

    const int nb = in_sizes[0];   // 2048
    fused4<<<nb, 256, 0, stream>>>(tp, loc, emb, st, loc_emb, noise, tstep,
                                   w1, w2b, te_tab, T1t, te_t, T2w3,
                                   b2, wc, alpha_hat, out);
}